// Round 3
// baseline (61.354 us; speedup 1.0000x reference)
//
#include <hip/hip_runtime.h>
#include <math.h>

#define N_TOK 2048          // tokens per modality (64*32)
#define NMOD  3
#define NTOT  6144          // N_TOK * NMOD
#define D     256
#define INV_TAU 10.0f

#define BM 128              // output tile (rows == cols)
#define BK 64               // k-step (64 bf16 = 128 B rows -> 8x16B swizzle slots)
#define NBLK (NTOT / BM)    // 48
#define NUPPER (NBLK * (NBLK + 1) / 2)   // 1176 upper-tri blocks

typedef float  f32x4  __attribute__((ext_vector_type(4)));
typedef short  bf16x8 __attribute__((ext_vector_type(8)));

// ------------------------------------------------------------- helpers
__device__ __forceinline__ unsigned short f2bf(float x) {
    unsigned int u = __float_as_uint(x);
    unsigned int r = (u + 0x7fffu + ((u >> 16) & 1u)) >> 16;   // RNE
    return (unsigned short)r;
}

__device__ __forceinline__ void gload16(const void* g, void* s) {
    __builtin_amdgcn_global_load_lds(
        (const __attribute__((address_space(1))) void*)g,
        (__attribute__((address_space(3))) void*)s, 16, 0, 0);
}

// ------------------------------------------------------------- normalize + bf16
__global__ void norm_kernel(const float* __restrict__ a,
                            const float* __restrict__ b,
                            const float* __restrict__ c,
                            unsigned short* __restrict__ H) {
    int row = blockIdx.x;
    const float* src;
    if (row < N_TOK)            src = a + (size_t)row * D;
    else if (row < 2 * N_TOK)   src = b + (size_t)(row - N_TOK) * D;
    else                        src = c + (size_t)(row - 2 * N_TOK) * D;

    int t = threadIdx.x;                 // 256 threads, one element each
    float v = src[t];
    float ss = v * v;
    #pragma unroll
    for (int o = 32; o > 0; o >>= 1) ss += __shfl_down(ss, o, 64);
    __shared__ float red[4];
    int lane = t & 63, w = t >> 6;
    if (lane == 0) red[w] = ss;
    __syncthreads();
    float tot = red[0] + red[1] + red[2] + red[3];
    float inv = rsqrtf(fmaxf(tot, 1e-16f));
    H[(size_t)row * D + t] = f2bf(v * inv);
}

// ------------------------------------------------------------- symmetric bf16 MFMA GEMM
// C = F F^T. Only upper-tri blocks (br<=bc) computed; off-diag tiles are
// stored twice (direct + LDS-transposed mirror). Fused exp-rowsums:
//   partials[bc][gr0+row]  (direct)   and   partials[br][gc0+col]  (mirror)
// cover every (colblock,row) slot exactly once.
__global__ __launch_bounds__(256)
void gemm_bf16_sym(const unsigned short* __restrict__ H,
                   float* __restrict__ C,
                   float* __restrict__ partials) {
    // decode linear index -> (br <= bc), column-major triangle
    int i = blockIdx.x;
    int bc = (int)((sqrtf(8.0f * (float)i + 1.0f) - 1.0f) * 0.5f);
    while ((bc + 1) * (bc + 2) / 2 <= i) ++bc;
    while (bc * (bc + 1) / 2 > i) --bc;
    const int br = i - bc * (bc + 1) / 2;
    const bool diag = (br == bc);

    __shared__ __align__(16) unsigned char smem[2 * BM * BK * 2];  // 32 KB
    unsigned short* As = (unsigned short*)smem;
    unsigned short* Bs = As + BM * BK;
    __shared__ float rowsum[BM][2];
    __shared__ float colsum[BM][2];

    const int t    = threadIdx.x;
    const int lane = t & 63;
    const int w    = t >> 6;      // wave id 0..3
    const int wm   = w >> 1;      // 0..1
    const int wn   = w & 1;       // 0..1

    f32x4 acc[4][4] = {};

    const unsigned short* Abase = H + (size_t)(br * BM) * D;
    const unsigned short* Bbase = H + (size_t)(bc * BM) * D;
    const unsigned short* BsR = diag ? As : Bs;   // diag: read B frags from As

    for (int kk = 0; kk < D; kk += BK) {
        // ---- stage tiles: linear LDS dest, inverse-swizzled global src
        #pragma unroll
        for (int i4 = 0; i4 < 4; ++i4) {
            int ch   = w * 4 + i4;                // 0..15 (1 KB chunks)
            int row  = ch * 8 + (lane >> 3);      // 0..127
            int slot = (lane & 7) ^ (row & 7);    // involution
            gload16(Abase + (size_t)row * D + kk + slot * 8,
                    (unsigned short*)As + ch * 512);
            if (!diag)
                gload16(Bbase + (size_t)row * D + kk + slot * 8,
                        (unsigned short*)Bs + ch * 512);
        }
        __syncthreads();

        // ---- compute: 2 k-halves of 32
        #pragma unroll
        for (int kh = 0; kh < 2; ++kh) {
            bf16x8 a[4], b[4];
            #pragma unroll
            for (int m = 0; m < 4; ++m) {
                int row  = wm * 64 + m * 16 + (lane & 15);
                int slot = (kh * 4 + (lane >> 4)) ^ (row & 7);
                a[m] = *(const bf16x8*)&As[row * 64 + slot * 8];
            }
            #pragma unroll
            for (int n = 0; n < 4; ++n) {
                int row  = wn * 64 + n * 16 + (lane & 15);
                int slot = (kh * 4 + (lane >> 4)) ^ (row & 7);
                b[n] = *(const bf16x8*)&BsR[row * 64 + slot * 8];
            }
            #pragma unroll
            for (int m = 0; m < 4; ++m)
                #pragma unroll
                for (int n = 0; n < 4; ++n)
                    acc[m][n] = __builtin_amdgcn_mfma_f32_16x16x32_bf16(
                        a[m], b[n], acc[m][n], 0, 0, 0);
        }
        __syncthreads();
    }

    // ---- epilogue: direct store + row/col exp partials
    const int gr0 = br * BM, gc0 = bc * BM;
    float rs[4][4];
    float cs[4];
    #pragma unroll
    for (int m = 0; m < 4; ++m)
        #pragma unroll
        for (int j = 0; j < 4; ++j) rs[m][j] = 0.0f;
    #pragma unroll
    for (int n = 0; n < 4; ++n) cs[n] = 0.0f;

    #pragma unroll
    for (int m = 0; m < 4; ++m) {
        #pragma unroll
        for (int n = 0; n < 4; ++n) {
            #pragma unroll
            for (int j = 0; j < 4; ++j) {
                int rl = wm * 64 + m * 16 + (lane >> 4) * 4 + j;
                int cl = wn * 64 + n * 16 + (lane & 15);
                float v = acc[m][n][j];
                C[(size_t)(gr0 + rl) * NTOT + gc0 + cl] = v;
                float e = __expf(v * INV_TAU);
                if (gr0 + rl == gc0 + cl) e = 0.0f;   // mask diagonal
                rs[m][j] += e;
                cs[n]    += e;
            }
        }
    }
    // row partials: reduce across lanes sharing rl (vary lane bits 0..3)
    #pragma unroll
    for (int m = 0; m < 4; ++m)
        #pragma unroll
        for (int j = 0; j < 4; ++j) {
            float s = rs[m][j];
            s += __shfl_xor(s, 1, 64);
            s += __shfl_xor(s, 2, 64);
            s += __shfl_xor(s, 4, 64);
            s += __shfl_xor(s, 8, 64);
            rs[m][j] = s;
        }
    if ((lane & 15) == 0) {
        #pragma unroll
        for (int m = 0; m < 4; ++m)
            #pragma unroll
            for (int j = 0; j < 4; ++j)
                rowsum[wm * 64 + m * 16 + (lane >> 4) * 4 + j][wn] = rs[m][j];
    }
    // col partials: reduce across lanes sharing cl (vary lane bits 4..5)
    if (!diag) {
        #pragma unroll
        for (int n = 0; n < 4; ++n) {
            float s = cs[n];
            s += __shfl_xor(s, 16, 64);
            s += __shfl_xor(s, 32, 64);
            cs[n] = s;
        }
        if (lane < 16) {
            #pragma unroll
            for (int n = 0; n < 4; ++n)
                colsum[wn * 64 + n * 16 + lane][wm] = cs[n];
        }
    }
    __syncthreads();
    if (t < BM) {
        partials[(size_t)bc * NTOT + gr0 + t] = rowsum[t][0] + rowsum[t][1];
        if (!diag)
            partials[(size_t)br * NTOT + gc0 + t] = colsum[t][0] + colsum[t][1];
    }

    // ---- mirror store via LDS transpose (reuse As/Bs: 32 KB = 64x128 f32)
    if (!diag) {
        float* tr = (float*)smem;
        #pragma unroll
        for (int half = 0; half < 2; ++half) {
            __syncthreads();
            if (wn == half) {
                #pragma unroll
                for (int m = 0; m < 4; ++m)
                    #pragma unroll
                    for (int n = 0; n < 4; ++n)
                        #pragma unroll
                        for (int j = 0; j < 4; ++j) {
                            int clh = n * 16 + (lane & 15);           // 0..63
                            int rl  = wm * 64 + m * 16 + (lane >> 4) * 4 + j;
                            tr[clh * 128 + (rl ^ ((clh & 7) << 2))] = acc[m][n][j];
                        }
            }
            __syncthreads();
            int r2 = t >> 7;          // 0..1
            int c  = t & 127;
            #pragma unroll 4
            for (int s = 0; s < 32; ++s) {
                int r = r2 + s * 2;   // 0..63
                float v = tr[r * 128 + (c ^ ((r & 7) << 2))];
                C[(size_t)(gc0 + half * 64 + r) * NTOT + gr0 + c] = v;
            }
        }
    }
}

// ------------------------------------------------------------- combine per-row
__global__ void loss_combine(const float* __restrict__ C,
                             const float* __restrict__ partials,
                             float* __restrict__ blocksum) {
    int r = blockIdx.x * 256 + threadIdx.x;   // 24 blocks x 256
    float s = 0.0f;
    #pragma unroll 8
    for (int b = 0; b < NBLK; ++b) s += partials[(size_t)b * NTOT + r];

    int k = r >> 11;          // r / 2048
    int i = r & 2047;
    float ps = 0.0f;
    #pragma unroll
    for (int j = 0; j < NMOD; ++j)
        if (j != k) ps += __expf(INV_TAU * C[(size_t)r * NTOT + i + j * N_TOK]);

    float rl = __logf(s) - __logf(ps);

    #pragma unroll
    for (int o = 32; o > 0; o >>= 1) rl += __shfl_down(rl, o, 64);
    __shared__ float red[4];
    int lane = threadIdx.x & 63, w = threadIdx.x >> 6;
    if (lane == 0) red[w] = rl;
    __syncthreads();
    if (threadIdx.x == 0)
        blocksum[blockIdx.x] = red[0] + red[1] + red[2] + red[3];
}

__global__ void final_sum(const float* __restrict__ blocksum, float* __restrict__ out) {
    int t = threadIdx.x;   // 64 threads
    float s = (t < 24) ? blocksum[t] : 0.0f;
    #pragma unroll
    for (int o = 32; o > 0; o >>= 1) s += __shfl_down(s, o, 64);
    if (t == 0) out[0] = s / (float)NTOT;
}

// ------------------------------------------------------------- launch
extern "C" void kernel_launch(void* const* d_in, const int* in_sizes, int n_in,
                              void* d_out, int out_size, void* d_ws, size_t ws_size,
                              hipStream_t stream) {
    const float* aerial = (const float*)d_in[0];
    const float* s2     = (const float*)d_in[1];
    const float* s1     = (const float*)d_in[2];
    float* out = (float*)d_out;

    unsigned short* H   = (unsigned short*)d_ws;                 // 6144*256 bf16 = 3 MB
    float* partials     = (float*)((char*)d_ws + (size_t)NTOT * D * 2);  // [48][6144] f32
    float* blocksum     = partials + (size_t)NBLK * NTOT;        // 24 floats
    float* C            = out + 1;                               // logits 6144x6144

    norm_kernel<<<NTOT, 256, 0, stream>>>(aerial, s2, s1, H);

    gemm_bf16_sym<<<NUPPER, 256, 0, stream>>>(H, C, partials);

    loss_combine<<<NTOT / 256, 256, 0, stream>>>(C, partials, blocksum);
    final_sum<<<1, 64, 0, stream>>>(blocksum, out);
}